// Round 10
// baseline (658.120 us; speedup 1.0000x reference)
//
#include <hip/hip_runtime.h>

typedef unsigned short u16;
typedef __bf16 bf16x8 __attribute__((ext_vector_type(8)));
typedef float f32x4 __attribute__((ext_vector_type(4)));
typedef u16 u16x8 __attribute__((ext_vector_type(8)));
typedef u16 u16x4 __attribute__((ext_vector_type(4)));

#define T_STEPS 64
#define BATCH 32
#define HDIM 1024
#define EDIM 512
#define VDIM 32000
#define GDIM 4096  // 4*H

// fp32 -> bf16 round-to-nearest-even (matches XLA convert)
__device__ __forceinline__ u16 f2b(float v) {
  unsigned x = __float_as_uint(v);
  return (u16)((x + 0x7fffu + ((x >> 16) & 1u)) >> 16);
}

// overflow-safe fast tanh: tanh(x) = sign(x) * (1 - 2/(e^{2|x|}+1))
__device__ __forceinline__ float ftanh(float x) {
  float ax = fabsf(x);
  float e = __expf(2.f * ax);  // inf for large ax -> t = 1
  float t = 1.f - 2.f / (e + 1.f);
  return copysignf(t, x);
}

// async global->LDS, 16B per lane; lds dest = wave-uniform base + lane*16
__device__ __forceinline__ void gload16(const void* g, void* l) {
  __builtin_amdgcn_global_load_lds(
      (const __attribute__((address_space(1))) void*)g,
      (__attribute__((address_space(3))) void*)l, 16, 0, 0);
}

__device__ __forceinline__ f32x4 mfma16(bf16x8 a, bf16x8 b, f32x4 c) {
  return __builtin_amdgcn_mfma_f32_16x16x32_bf16(a, b, c, 0, 0, 0);
}

// ---------------- prep kernels ----------------

// blocks 0..1023: emb gather (2 tokens/block); 1024..1151: h0/c init
__global__ __launch_bounds__(256) void gather_init_k(
    const int* __restrict__ x, const float* __restrict__ emb,
    u16* __restrict__ A, const float* __restrict__ h0,
    const float* __restrict__ c0, u16* __restrict__ h0b,
    float* __restrict__ c_ws) {
  int tid = threadIdx.x;
  if (blockIdx.x < 1024) {
    int bt = blockIdx.x * 2 + (tid >> 7);
    int tok = x[bt];
    const float4* src = (const float4*)(emb + (size_t)tok * EDIM);
    u16x4* dst = (u16x4*)(A + (size_t)bt * EDIM);
    int i = tid & 127;
    float4 v = src[i];
    u16x4 o = {f2b(v.x), f2b(v.y), f2b(v.z), f2b(v.w)};
    dst[i] = o;
  } else {
    int i = (blockIdx.x - 1024) * 256 + tid;  // 32768 total
    h0b[i] = f2b(h0[i]);
    c_ws[i] = c0[i];
  }
}

// in: fp32 [K][N] row-major -> out: bf16 [N][K] row-major.
// f32 LDS tile [64][65]: float4 loads -> contiguous float4 LDS writes
// (conflict-free); reads ~2-way; f2b on read side; u16x8 stores.
__global__ __launch_bounds__(256) void transpose_cvt_k(
    const float* __restrict__ in, u16* __restrict__ out, int K, int N) {
  __shared__ float tile[64][65];  // [k][n]
  int n0 = blockIdx.x * 64, k0 = blockIdx.y * 64;
  int tid = threadIdx.x;
  int r0 = tid >> 4;          // 0..15 (k row group)
  int c4 = (tid & 15) * 4;    // n col (float4)
#pragma unroll
  for (int rr = 0; rr < 4; ++rr) {
    int r = rr * 16 + r0;  // k index within tile
    float4 v = *reinterpret_cast<const float4*>(
        &in[(size_t)(k0 + r) * N + n0 + c4]);
    *reinterpret_cast<float4*>(&tile[r][c4]) = v;
  }
  __syncthreads();
  int wr2 = tid >> 3, c8 = (tid & 7) * 8;
#pragma unroll
  for (int rr = 0; rr < 2; ++rr) {
    int r = rr * 32 + wr2;  // n index within tile
    u16x8 o;
#pragma unroll
    for (int k = 0; k < 8; ++k) o[k] = f2b(tile[c8 + k][r]);
    *reinterpret_cast<u16x8*>(&out[(size_t)(n0 + r) * K + k0 + c8]) = o;
  }
}

// U transpose with gate-permuted output rows: out row pn = m*16 + g*4 + j
// for input col n = g*1024 + m*4 + j.
__global__ __launch_bounds__(256) void transpose_cvt_permU_k(
    const float* __restrict__ in, u16* __restrict__ out) {
  const int K = HDIM, N = GDIM;
  __shared__ float tile[64][65];
  int n0 = blockIdx.x * 64, k0 = blockIdx.y * 64;
  int tid = threadIdx.x;
  int r0 = tid >> 4;
  int c4 = (tid & 15) * 4;
#pragma unroll
  for (int rr = 0; rr < 4; ++rr) {
    int r = rr * 16 + r0;
    float4 v = *reinterpret_cast<const float4*>(
        &in[(size_t)(k0 + r) * N + n0 + c4]);
    *reinterpret_cast<float4*>(&tile[r][c4]) = v;
  }
  __syncthreads();
  int wr2 = tid >> 3, c8 = (tid & 7) * 8;
#pragma unroll
  for (int rr = 0; rr < 2; ++rr) {
    int r = rr * 32 + wr2;
    int n = n0 + r;
    int g = n >> 10, c = n & 1023;
    int pn = ((c >> 2) << 4) + (g << 2) + (c & 3);
    u16x8 o;
#pragma unroll
    for (int k = 0; k < 8; ++k) o[k] = f2b(tile[c8 + k][r]);
    *reinterpret_cast<u16x8*>(&out[(size_t)pn * K + k0 + c8]) = o;
  }
}

// ---------------- 256x256 4-phase GEMM (merged N-halves) ----------------
// 512 threads = 8 waves (2M x 4N). BK=64, 2 K-tiles/iter, 4 phases/iter.
// Per K-tile: PH_FULL reads af[mih=0] + ALL B fragments (held in 32 VGPRs),
// PH_A reads only af[mih=1], reuses bfr. Fixed buffer roles: even K-tiles
// in bd, odd in bo. Ledger: outstanding 4 ->P1 8 ->P2 12 -VMW4-> 4 ->P3 8
// ->P4 12 -VMW4-> 4. WAR: each stage targets a region whose last reader
// finished >=1 barrier earlier. RAW: each region VMW4-drained >=1 phase
// before first read. Last iteration peeled (P2 = VMW0, P3/P4 no stage).
// Epilogue: per-wave LDS transpose -> float4 coalesced C stores.

#define STG_A(dst, h, kb)                                              \
  do {                                                                 \
    gload16(Abytes + offA[h][0] + (kb), (dst) + (h) * 16384 + w * 1024); \
    gload16(Abytes + offA[h][1] + (kb),                                \
            (dst) + (h) * 16384 + 8192 + w * 1024);                    \
  } while (0)
#define STG_B(dst, h, kb)                                              \
  do {                                                                 \
    gload16(Bbytes + offB[h][0] + (kb),                                \
            (dst) + 32768 + (h) * 16384 + w * 1024);                   \
    gload16(Bbytes + offB[h][1] + (kb),                                \
            (dst) + 32768 + (h) * 16384 + 8192 + w * 1024);            \
  } while (0)
#define VMW4 asm volatile("s_waitcnt vmcnt(4)" ::: "memory")
#define VMW0 asm volatile("s_waitcnt vmcnt(0)" ::: "memory")

#define MFMA_BLOCK(mih)                                                   \
  do {                                                                    \
    __builtin_amdgcn_s_setprio(1);                                        \
    _Pragma("unroll") for (int u = 0; u < 4; ++u)                         \
        _Pragma("unroll") for (int v = 0; v < 4; ++v) {                   \
      acc[(mih)*4 + u][v] = mfma16(af[u][0], bfr[v][0], acc[(mih)*4 + u][v]); \
      acc[(mih)*4 + u][v] = mfma16(af[u][1], bfr[v][1], acc[(mih)*4 + u][v]); \
    }                                                                     \
    __builtin_amdgcn_s_setprio(0);                                        \
  } while (0)

// full phase: read af (mih) + all bfr (kept for the sibling PH_A phase)
#define PH_FULL(cur, mih, STG, WAIT)                                      \
  do {                                                                    \
    bf16x8 af[4][2];                                                      \
    _Pragma("unroll") for (int u = 0; u < 4; ++u) {                       \
      af[u][0] = *reinterpret_cast<const bf16x8*>((cur) +                 \
                                                  aoff[(mih)*4 + u][0]);  \
      af[u][1] = *reinterpret_cast<const bf16x8*>((cur) +                 \
                                                  aoff[(mih)*4 + u][1]);  \
    }                                                                     \
    _Pragma("unroll") for (int v = 0; v < 4; ++v) {                       \
      bfr[v][0] = *reinterpret_cast<const bf16x8*>((cur) + boff[v][0]);   \
      bfr[v][1] = *reinterpret_cast<const bf16x8*>((cur) + boff[v][1]);   \
    }                                                                     \
    STG;                                                                  \
    __builtin_amdgcn_s_barrier();                                         \
    asm volatile("s_waitcnt lgkmcnt(0)" ::: "memory");                    \
    MFMA_BLOCK(mih);                                                      \
    WAIT;                                                                 \
    __builtin_amdgcn_s_barrier();                                         \
  } while (0)

// A-only phase: bfr reused from the preceding PH_FULL on the same buffer
#define PH_A(cur, mih, STG, WAIT)                                         \
  do {                                                                    \
    bf16x8 af[4][2];                                                      \
    _Pragma("unroll") for (int u = 0; u < 4; ++u) {                       \
      af[u][0] = *reinterpret_cast<const bf16x8*>((cur) +                 \
                                                  aoff[(mih)*4 + u][0]);  \
      af[u][1] = *reinterpret_cast<const bf16x8*>((cur) +                 \
                                                  aoff[(mih)*4 + u][1]);  \
    }                                                                     \
    STG;                                                                  \
    __builtin_amdgcn_s_barrier();                                         \
    asm volatile("s_waitcnt lgkmcnt(0)" ::: "memory");                    \
    MFMA_BLOCK(mih);                                                      \
    WAIT;                                                                 \
    __builtin_amdgcn_s_barrier();                                         \
  } while (0)

__global__ __launch_bounds__(512, 2) void gemm256_k(
    const u16* __restrict__ A,    // [M][K] bf16
    const u16* __restrict__ BT,   // [N][K] bf16
    const float* __restrict__ bias,
    float* __restrict__ C,        // [M][N] fp32
    int M, int N, int K) {
  __shared__ __attribute__((aligned(1024))) char smem[131072];
  const int tid = threadIdx.x;
  const int w = tid >> 6, lane = tid & 63;
  const int lo16 = lane & 15, hi4 = lane >> 4;
  const int wr = w >> 2, wc = w & 3;

  // XCD-bijective swizzle (gridDim.x % 8 == 0) + M-major panel mapping
  const int cpx = gridDim.x >> 3;
  const int bid = blockIdx.x;
  const int swz = (bid & 7) * cpx + (bid >> 3);
  const int nmb = M >> 8;
  const int m0 = (swz % nmb) << 8, n0 = (swz / nmb) << 8;

  const char* Abytes = (const char*)A;
  const char* Bbytes = (const char*)BT;
  const int K2 = K * 2;

  // per-thread stage source offsets (inverse st_16x32 swizzle decode)
  int offA[2][2], offB[2][2];
#pragma unroll
  for (int h = 0; h < 2; ++h)
#pragma unroll
    for (int i = 0; i < 2; ++i) {
      int o = h * 16384 + (i * 512 + tid) * 16;
      int s = o >> 10, q = o & 1023;
      int qp = q ^ (((q >> 9) & 1) << 5);
      int row = ((s >> 1) << 4) + (qp >> 6);
      int colb = ((s & 1) << 6) + (qp & 63);
      offA[h][i] = (m0 + row) * K2 + colb;
      offB[h][i] = (n0 + row) * K2 + colb;
    }

  // per-thread fragment LDS byte offsets (swizzled read addresses)
  int aoff[8][2], boff[4][2];
#pragma unroll
  for (int mi = 0; mi < 8; ++mi)
#pragma unroll
    for (int kk = 0; kk < 2; ++kk) {
      int r = (mi >> 2) * 128 + wr * 64 + (mi & 3) * 16 + lo16;
      int q = (r & 15) * 64 + hi4 * 16;
      int qs = q ^ (((q >> 9) & 1) << 5);
      aoff[mi][kk] = (((r >> 4) << 1) + kk) * 1024 + qs;
    }
#pragma unroll
  for (int nj = 0; nj < 4; ++nj)
#pragma unroll
    for (int kk = 0; kk < 2; ++kk) {
      int r = (nj >> 1) * 128 + wc * 32 + (nj & 1) * 16 + lo16;
      int q = (r & 15) * 64 + hi4 * 16;
      int qs = q ^ (((q >> 9) & 1) << 5);
      boff[nj][kk] = 32768 + (((r >> 4) << 1) + kk) * 1024 + qs;
    }

  f32x4 acc[8][4] = {};
  bf16x8 bfr[4][2];                // B fragments, live across phase pairs
  char* const bd = smem;           // even K-tiles — roles never swap
  char* const bo = smem + 65536;   // odd K-tiles

  // prologue: kt0 complete in bd + kt1 halves A0,B0 in bo; drain kt0
  STG_A(bd, 0, 0);
  STG_B(bd, 0, 0);
  STG_A(bd, 1, 0);
  STG_B(bd, 1, 0);
  STG_A(bo, 0, 128);
  STG_B(bo, 0, 128);
  VMW4;
  __builtin_amdgcn_s_barrier();

  const int NITER = K >> 7;  // two BK=64 tiles per iteration (K % 128 == 0)
  for (int it = 0; it < NITER - 1; ++it) {
    const int k1 = (it * 128 + 64) * 2;
    const int k2 = (it * 128 + 128) * 2;
    const int k3 = (it * 128 + 192) * 2;
    PH_FULL(bd, 0, { STG_A(bo, 1, k1); STG_B(bo, 1, k1); }, ((void)0));
    PH_A(bd, 1, { STG_A(bd, 0, k2); STG_B(bd, 0, k2); }, VMW4);
    PH_FULL(bo, 0, { STG_A(bd, 1, k2); STG_B(bd, 1, k2); }, ((void)0));
    PH_A(bo, 1, { STG_A(bo, 0, k3); STG_B(bo, 0, k3); }, VMW4);
  }
  {  // peeled last iteration
    const int k1 = ((NITER - 1) * 128 + 64) * 2;
    PH_FULL(bd, 0, { STG_A(bo, 1, k1); STG_B(bo, 1, k1); }, ((void)0));
    PH_A(bd, 1, ((void)0), VMW0);
    PH_FULL(bo, 0, ((void)0), ((void)0));
    PH_A(bo, 1, ((void)0), ((void)0));
  }

  // ---- epilogue: per-wave LDS transpose -> coalesced float4 stores ----
  // wave region [16][66] f32 (4224 B); per mi: 16x64 slab. col layout:
  // LDS col c<32 -> global col n0+wc*32+c ; c>=32 -> +96 more (nj>>1 jump).
  float* lds_ep = reinterpret_cast<float*>(smem) + w * (16 * 66);
  const int erow = lane >> 4;   // 0..3
  const int ecol = lane & 15;   // 16B chunk
  const int gcol = n0 + wc * 32 + ((ecol >= 8) ? 96 : 0) + ecol * 4;
#pragma unroll
  for (int mi = 0; mi < 8; ++mi) {
    int rowbase = m0 + (mi >> 2) * 128 + wr * 64 + (mi & 3) * 16;
#pragma unroll
    for (int nj = 0; nj < 4; ++nj) {
      int lc = (nj >> 1) * 32 + (nj & 1) * 16 + lo16;
      float bv =
          bias ? bias[n0 + (nj >> 1) * 128 + wc * 32 + (nj & 1) * 16 + lo16]
               : 0.f;
#pragma unroll
      for (int j = 0; j < 4; ++j)
        lds_ep[(hi4 * 4 + j) * 66 + lc] = acc[mi][nj][j] + bv;
    }
    asm volatile("s_waitcnt lgkmcnt(0)" ::: "memory");
#pragma unroll
    for (int rr = 0; rr < 4; ++rr) {
      int r = rr * 4 + erow;
      float4 v = *reinterpret_cast<const float4*>(&lds_ep[r * 66 + ecol * 4]);
      *reinterpret_cast<float4*>(&C[(size_t)(rowbase + r) * N + gcol]) = v;
    }
    asm volatile("s_waitcnt lgkmcnt(0)" ::: "memory");  // reads before rewrite
  }
}

// ---------------- slim LSTM step (round-5 form, best measured) ----------
// 512 blocks x 256 threads (2 blocks/CU). Block = one 16x16 output tile;
// 4 waves split K=1024; operands direct from global (L2-hot); xW loads
// hoisted; seq doubles as the h history.

__global__ __launch_bounds__(256) void lstm_step2_k(
    const float* __restrict__ xW,    // [2048][4096] (bias included)
    const u16* __restrict__ h_src,   // bf16, row b at h_src + b*h_stride
    int h_stride,
    const u16* __restrict__ UT2,     // [4096 permuted][1024] bf16
    float* __restrict__ c_ws,        // [32][1024] fp32 state (in/out)
    u16* __restrict__ seq,           // [2048][1024] bf16
    float* __restrict__ out_hc,      // final h,c (fp32) or nullptr
    int t) {
  __shared__ float Zs[4][16][17];
  const int tid = threadIdx.x;
  const int w = tid >> 6, lane = tid & 63;
  const int lo16 = lane & 15, hi4 = lane >> 4;
  const int zt = blockIdx.x >> 1;   // 0..255
  const int bt = blockIdx.x & 1;    // 0..1

  // hoisted xW prefetch (consumed after the z-reduce barrier)
  const int bb = tid >> 2, jg = tid & 3;
  float xw0 = 0.f, xw1 = 0.f, xw2 = 0.f, xw3 = 0.f;
  if (tid < 64) {
    const float* xrow =
        xW + (size_t)((bt * 16 + bb) * T_STEPS + t) * GDIM + zt * 4 + jg;
    xw0 = xrow[0];
    xw1 = xrow[1024];
    xw2 = xrow[2048];
    xw3 = xrow[3072];
  }

  const u16* arow = h_src + (size_t)(bt * 16 + lo16) * h_stride;
  const u16* brow = UT2 + (size_t)(zt * 16 + lo16) * HDIM;

  f32x4 acc = {};
#pragma unroll
  for (int kc = 0; kc < 8; ++kc) {
    int k = w * 256 + kc * 32 + hi4 * 8;
    bf16x8 a = *reinterpret_cast<const bf16x8*>(arow + k);
    bf16x8 b = *reinterpret_cast<const bf16x8*>(brow + k);
    acc = mfma16(a, b, acc);
  }
#pragma unroll
  for (int j = 0; j < 4; ++j) Zs[w][hi4 * 4 + j][lo16] = acc[j];
  __syncthreads();

  if (tid < 64) {
    int b = bt * 16 + bb;
    int hcol = zt * 4 + jg;
    float z[4] = {xw0, xw1, xw2, xw3};
#pragma unroll
    for (int g = 0; g < 4; ++g)
#pragma unroll
      for (int ww = 0; ww < 4; ++ww) z[g] += Zs[ww][bb][g * 4 + jg];
    size_t cidx = (size_t)b * HDIM + hcol;
    float c_old = c_ws[cidx];
    float ig = 1.f / (1.f + __expf(-z[0]));
    float fg = 1.f / (1.f + __expf(-z[1]));
    float gg = ftanh(z[2]);
    float og = 1.f / (1.f + __expf(-z[3]));
    float cn = fg * c_old + ig * gg;
    float hn = og * ftanh(cn);
    c_ws[cidx] = cn;
    seq[(size_t)(b * T_STEPS + t) * HDIM + hcol] = f2b(hn);
    if (out_hc) {
      out_hc[cidx] = hn;
      out_hc[BATCH * HDIM + cidx] = cn;
    }
  }
}

// ---------------- launcher ----------------

extern "C" void kernel_launch(void* const* d_in, const int* in_sizes, int n_in,
                              void* d_out, int out_size, void* d_ws,
                              size_t ws_size, hipStream_t stream) {
  const int* x = (const int*)d_in[0];
  const float* state_h = (const float*)d_in[1];
  const float* state_c = (const float*)d_in[2];
  const float* emb = (const float*)d_in[3];
  const float* W = (const float*)d_in[4];
  const float* U = (const float*)d_in[5];
  const float* bvec = (const float*)d_in[6];
  const float* dW = (const float*)d_in[7];
  const float* db = (const float*)d_in[8];
  float* out = (float*)d_out;
  char* ws = (char*)d_ws;

  size_t off = 0;
  auto alloc = [&](size_t bytes) {
    void* p = ws + off;
    off += (bytes + 255) & ~(size_t)255;
    return p;
  };
  u16* A_emb = (u16*)alloc(2048ull * EDIM * 2);      //  2.0 MB
  u16* WbT   = (u16*)alloc((size_t)GDIM * EDIM * 2); //  4.0 MB
  u16* UT2   = (u16*)alloc((size_t)GDIM * HDIM * 2); //  8.4 MB (permuted)
  u16* DbT   = (u16*)alloc((size_t)VDIM * HDIM * 2); // 65.5 MB
  float* xW  = (float*)alloc(2048ull * GDIM * 4);    // 33.6 MB
  u16* seq   = (u16*)alloc(2048ull * HDIM * 2);      //  4.2 MB
  u16* h0b   = (u16*)alloc((size_t)BATCH * HDIM * 2);
  float* c_ws = (float*)alloc((size_t)BATCH * HDIM * 4);
  if (off > ws_size) return;  // ~117.8 MB needed

  gather_init_k<<<1152, 256, 0, stream>>>(x, emb, A_emb, state_h, state_c,
                                          h0b, c_ws);
  transpose_cvt_k<<<dim3(GDIM / 64, EDIM / 64), 256, 0, stream>>>(W, WbT, EDIM, GDIM);
  transpose_cvt_permU_k<<<dim3(GDIM / 64, HDIM / 64), 256, 0, stream>>>(U, UT2);
  transpose_cvt_k<<<dim3(VDIM / 64, HDIM / 64), 256, 0, stream>>>(dW, DbT, HDIM, VDIM);

  // xW = emb @ W + b : [2048][4096] via the 256x256 pipeline (K=512)
  gemm256_k<<<dim3((2048 / 256) * (GDIM / 256)), 512, 0, stream>>>(
      A_emb, WbT, bvec, xW, 2048, GDIM, EDIM);

  // LSTM scan: 64 slim step kernels; seq is the h history
  for (int t = 0; t < T_STEPS; ++t) {
    const u16* h_src = (t == 0) ? h0b : (seq + (size_t)(t - 1) * HDIM);
    int h_stride = (t == 0) ? HDIM : T_STEPS * HDIM;
    float* outhc = (t == T_STEPS - 1) ? (out + 65536000ull) : nullptr;
    lstm_step2_k<<<512, 256, 0, stream>>>(xW, h_src, h_stride, UT2, c_ws, seq,
                                          outhc, t);
  }

  // logits = seq @ dense_W + dense_b : [2048][32000], 8x125=1000 blocks
  gemm256_k<<<dim3((2048 / 256) * (VDIM / 256)), 512, 0, stream>>>(
      seq, DbT, db, out, 2048, VDIM, HDIM);
}

// Round 11
// 649.805 us; speedup vs baseline: 1.0128x; 1.0128x over previous
//
#include <hip/hip_runtime.h>

typedef unsigned short u16;
typedef __bf16 bf16x8 __attribute__((ext_vector_type(8)));
typedef float f32x4 __attribute__((ext_vector_type(4)));
typedef u16 u16x8 __attribute__((ext_vector_type(8)));
typedef u16 u16x4 __attribute__((ext_vector_type(4)));

#define T_STEPS 64
#define BATCH 32
#define HDIM 1024
#define EDIM 512
#define VDIM 32000
#define GDIM 4096  // 4*H

// fp32 -> bf16 round-to-nearest-even (matches XLA convert)
__device__ __forceinline__ u16 f2b(float v) {
  unsigned x = __float_as_uint(v);
  return (u16)((x + 0x7fffu + ((x >> 16) & 1u)) >> 16);
}

// overflow-safe fast tanh: tanh(x) = sign(x) * (1 - 2/(e^{2|x|}+1))
__device__ __forceinline__ float ftanh(float x) {
  float ax = fabsf(x);
  float e = __expf(2.f * ax);  // inf for large ax -> t = 1
  float t = 1.f - 2.f / (e + 1.f);
  return copysignf(t, x);
}

// async global->LDS, 16B per lane; lds dest = wave-uniform base + lane*16
__device__ __forceinline__ void gload16(const void* g, void* l) {
  __builtin_amdgcn_global_load_lds(
      (const __attribute__((address_space(1))) void*)g,
      (__attribute__((address_space(3))) void*)l, 16, 0, 0);
}

__device__ __forceinline__ f32x4 mfma16(bf16x8 a, bf16x8 b, f32x4 c) {
  return __builtin_amdgcn_mfma_f32_16x16x32_bf16(a, b, c, 0, 0, 0);
}

// ---------------- prep kernels ----------------

// blocks 0..1023: emb gather (2 tokens/block); 1024..1151: h0/c init
__global__ __launch_bounds__(256) void gather_init_k(
    const int* __restrict__ x, const float* __restrict__ emb,
    u16* __restrict__ A, const float* __restrict__ h0,
    const float* __restrict__ c0, u16* __restrict__ h0b,
    float* __restrict__ c_ws) {
  int tid = threadIdx.x;
  if (blockIdx.x < 1024) {
    int bt = blockIdx.x * 2 + (tid >> 7);
    int tok = x[bt];
    const float4* src = (const float4*)(emb + (size_t)tok * EDIM);
    u16x4* dst = (u16x4*)(A + (size_t)bt * EDIM);
    int i = tid & 127;
    float4 v = src[i];
    u16x4 o = {f2b(v.x), f2b(v.y), f2b(v.z), f2b(v.w)};
    dst[i] = o;
  } else {
    int i = (blockIdx.x - 1024) * 256 + tid;  // 32768 total
    h0b[i] = f2b(h0[i]);
    c_ws[i] = c0[i];
  }
}

// in: fp32 [K][N] row-major -> out: bf16 [N][K] row-major.
// f32 LDS tile [64][65]: float4 loads -> contiguous float4 LDS writes
// (conflict-free); reads ~2-way; f2b on read side; u16x8 stores.
__global__ __launch_bounds__(256) void transpose_cvt_k(
    const float* __restrict__ in, u16* __restrict__ out, int K, int N) {
  __shared__ float tile[64][65];  // [k][n]
  int n0 = blockIdx.x * 64, k0 = blockIdx.y * 64;
  int tid = threadIdx.x;
  int r0 = tid >> 4;          // 0..15 (k row group)
  int c4 = (tid & 15) * 4;    // n col (float4)
#pragma unroll
  for (int rr = 0; rr < 4; ++rr) {
    int r = rr * 16 + r0;  // k index within tile
    float4 v = *reinterpret_cast<const float4*>(
        &in[(size_t)(k0 + r) * N + n0 + c4]);
    *reinterpret_cast<float4*>(&tile[r][c4]) = v;
  }
  __syncthreads();
  int wr2 = tid >> 3, c8 = (tid & 7) * 8;
#pragma unroll
  for (int rr = 0; rr < 2; ++rr) {
    int r = rr * 32 + wr2;  // n index within tile
    u16x8 o;
#pragma unroll
    for (int k = 0; k < 8; ++k) o[k] = f2b(tile[c8 + k][r]);
    *reinterpret_cast<u16x8*>(&out[(size_t)(n0 + r) * K + k0 + c8]) = o;
  }
}

// U transpose with gate-permuted output rows: out row pn = m*16 + g*4 + j
// for input col n = g*1024 + m*4 + j.
__global__ __launch_bounds__(256) void transpose_cvt_permU_k(
    const float* __restrict__ in, u16* __restrict__ out) {
  const int K = HDIM, N = GDIM;
  __shared__ float tile[64][65];
  int n0 = blockIdx.x * 64, k0 = blockIdx.y * 64;
  int tid = threadIdx.x;
  int r0 = tid >> 4;
  int c4 = (tid & 15) * 4;
#pragma unroll
  for (int rr = 0; rr < 4; ++rr) {
    int r = rr * 16 + r0;
    float4 v = *reinterpret_cast<const float4*>(
        &in[(size_t)(k0 + r) * N + n0 + c4]);
    *reinterpret_cast<float4*>(&tile[r][c4]) = v;
  }
  __syncthreads();
  int wr2 = tid >> 3, c8 = (tid & 7) * 8;
#pragma unroll
  for (int rr = 0; rr < 2; ++rr) {
    int r = rr * 32 + wr2;
    int n = n0 + r;
    int g = n >> 10, c = n & 1023;
    int pn = ((c >> 2) << 4) + (g << 2) + (c & 3);
    u16x8 o;
#pragma unroll
    for (int k = 0; k < 8; ++k) o[k] = f2b(tile[c8 + k][r]);
    *reinterpret_cast<u16x8*>(&out[(size_t)pn * K + k0 + c8]) = o;
  }
}

// ---------------- 256x256 4-phase GEMM (merged N-halves) ----------------
// 512 threads = 8 waves (2M x 4N). BK=64, 2 K-tiles/iter, 4 phases/iter.
// Per K-tile: PH_FULL reads af[mih=0] + ALL B fragments (held in 32 VGPRs),
// PH_A reads only af[mih=1], reuses bfr. Fixed buffer roles: even K-tiles
// in bd, odd in bo. Ledger: outstanding 4 ->P1 8 ->P2 12 -VMW4-> 4 ->P3 8
// ->P4 12 -VMW4-> 4. WAR: each stage targets a region whose last reader
// finished >=1 barrier earlier. RAW: each region VMW4-drained >=1 phase
// before first read. Last iteration peeled (P2 = VMW0, P3/P4 no stage).
// Direct C stores (round-8 best-measured epilogue; LDS-transpose epilogue
// measured slower). 771 TF @K=1024 = 91% of m248 reference — near this
// structure's ceiling.

#define STG_A(dst, h, kb)                                              \
  do {                                                                 \
    gload16(Abytes + offA[h][0] + (kb), (dst) + (h) * 16384 + w * 1024); \
    gload16(Abytes + offA[h][1] + (kb),                                \
            (dst) + (h) * 16384 + 8192 + w * 1024);                    \
  } while (0)
#define STG_B(dst, h, kb)                                              \
  do {                                                                 \
    gload16(Bbytes + offB[h][0] + (kb),                                \
            (dst) + 32768 + (h) * 16384 + w * 1024);                   \
    gload16(Bbytes + offB[h][1] + (kb),                                \
            (dst) + 32768 + (h) * 16384 + 8192 + w * 1024);            \
  } while (0)
#define VMW4 asm volatile("s_waitcnt vmcnt(4)" ::: "memory")
#define VMW0 asm volatile("s_waitcnt vmcnt(0)" ::: "memory")

#define MFMA_BLOCK(mih)                                                   \
  do {                                                                    \
    __builtin_amdgcn_s_setprio(1);                                        \
    _Pragma("unroll") for (int u = 0; u < 4; ++u)                         \
        _Pragma("unroll") for (int v = 0; v < 4; ++v) {                   \
      acc[(mih)*4 + u][v] = mfma16(af[u][0], bfr[v][0], acc[(mih)*4 + u][v]); \
      acc[(mih)*4 + u][v] = mfma16(af[u][1], bfr[v][1], acc[(mih)*4 + u][v]); \
    }                                                                     \
    __builtin_amdgcn_s_setprio(0);                                        \
  } while (0)

// full phase: read af (mih) + all bfr (kept for the sibling PH_A phase)
#define PH_FULL(cur, mih, STG, WAIT)                                      \
  do {                                                                    \
    bf16x8 af[4][2];                                                      \
    _Pragma("unroll") for (int u = 0; u < 4; ++u) {                       \
      af[u][0] = *reinterpret_cast<const bf16x8*>((cur) +                 \
                                                  aoff[(mih)*4 + u][0]);  \
      af[u][1] = *reinterpret_cast<const bf16x8*>((cur) +                 \
                                                  aoff[(mih)*4 + u][1]);  \
    }                                                                     \
    _Pragma("unroll") for (int v = 0; v < 4; ++v) {                       \
      bfr[v][0] = *reinterpret_cast<const bf16x8*>((cur) + boff[v][0]);   \
      bfr[v][1] = *reinterpret_cast<const bf16x8*>((cur) + boff[v][1]);   \
    }                                                                     \
    STG;                                                                  \
    __builtin_amdgcn_s_barrier();                                         \
    asm volatile("s_waitcnt lgkmcnt(0)" ::: "memory");                    \
    MFMA_BLOCK(mih);                                                      \
    WAIT;                                                                 \
    __builtin_amdgcn_s_barrier();                                         \
  } while (0)

// A-only phase: bfr reused from the preceding PH_FULL on the same buffer
#define PH_A(cur, mih, STG, WAIT)                                         \
  do {                                                                    \
    bf16x8 af[4][2];                                                      \
    _Pragma("unroll") for (int u = 0; u < 4; ++u) {                       \
      af[u][0] = *reinterpret_cast<const bf16x8*>((cur) +                 \
                                                  aoff[(mih)*4 + u][0]);  \
      af[u][1] = *reinterpret_cast<const bf16x8*>((cur) +                 \
                                                  aoff[(mih)*4 + u][1]);  \
    }                                                                     \
    STG;                                                                  \
    __builtin_amdgcn_s_barrier();                                         \
    asm volatile("s_waitcnt lgkmcnt(0)" ::: "memory");                    \
    MFMA_BLOCK(mih);                                                      \
    WAIT;                                                                 \
    __builtin_amdgcn_s_barrier();                                         \
  } while (0)

__global__ __launch_bounds__(512, 2) void gemm256_k(
    const u16* __restrict__ A,    // [M][K] bf16
    const u16* __restrict__ BT,   // [N][K] bf16
    const float* __restrict__ bias,
    float* __restrict__ C,        // [M][N] fp32
    int M, int N, int K) {
  __shared__ __attribute__((aligned(1024))) char smem[131072];
  const int tid = threadIdx.x;
  const int w = tid >> 6, lane = tid & 63;
  const int lo16 = lane & 15, hi4 = lane >> 4;
  const int wr = w >> 2, wc = w & 3;

  // XCD-bijective swizzle (gridDim.x % 8 == 0) + M-major panel mapping
  const int cpx = gridDim.x >> 3;
  const int bid = blockIdx.x;
  const int swz = (bid & 7) * cpx + (bid >> 3);
  const int nmb = M >> 8;
  const int m0 = (swz % nmb) << 8, n0 = (swz / nmb) << 8;

  const char* Abytes = (const char*)A;
  const char* Bbytes = (const char*)BT;
  const int K2 = K * 2;

  // per-thread stage source offsets (inverse st_16x32 swizzle decode)
  int offA[2][2], offB[2][2];
#pragma unroll
  for (int h = 0; h < 2; ++h)
#pragma unroll
    for (int i = 0; i < 2; ++i) {
      int o = h * 16384 + (i * 512 + tid) * 16;
      int s = o >> 10, q = o & 1023;
      int qp = q ^ (((q >> 9) & 1) << 5);
      int row = ((s >> 1) << 4) + (qp >> 6);
      int colb = ((s & 1) << 6) + (qp & 63);
      offA[h][i] = (m0 + row) * K2 + colb;
      offB[h][i] = (n0 + row) * K2 + colb;
    }

  // per-thread fragment LDS byte offsets (swizzled read addresses)
  int aoff[8][2], boff[4][2];
#pragma unroll
  for (int mi = 0; mi < 8; ++mi)
#pragma unroll
    for (int kk = 0; kk < 2; ++kk) {
      int r = (mi >> 2) * 128 + wr * 64 + (mi & 3) * 16 + lo16;
      int q = (r & 15) * 64 + hi4 * 16;
      int qs = q ^ (((q >> 9) & 1) << 5);
      aoff[mi][kk] = (((r >> 4) << 1) + kk) * 1024 + qs;
    }
#pragma unroll
  for (int nj = 0; nj < 4; ++nj)
#pragma unroll
    for (int kk = 0; kk < 2; ++kk) {
      int r = (nj >> 1) * 128 + wc * 32 + (nj & 1) * 16 + lo16;
      int q = (r & 15) * 64 + hi4 * 16;
      int qs = q ^ (((q >> 9) & 1) << 5);
      boff[nj][kk] = 32768 + (((r >> 4) << 1) + kk) * 1024 + qs;
    }

  f32x4 acc[8][4] = {};
  bf16x8 bfr[4][2];                // B fragments, live across phase pairs
  char* const bd = smem;           // even K-tiles — roles never swap
  char* const bo = smem + 65536;   // odd K-tiles

  // prologue: kt0 complete in bd + kt1 halves A0,B0 in bo; drain kt0
  STG_A(bd, 0, 0);
  STG_B(bd, 0, 0);
  STG_A(bd, 1, 0);
  STG_B(bd, 1, 0);
  STG_A(bo, 0, 128);
  STG_B(bo, 0, 128);
  VMW4;
  __builtin_amdgcn_s_barrier();

  const int NITER = K >> 7;  // two BK=64 tiles per iteration (K % 128 == 0)
  for (int it = 0; it < NITER - 1; ++it) {
    const int k1 = (it * 128 + 64) * 2;
    const int k2 = (it * 128 + 128) * 2;
    const int k3 = (it * 128 + 192) * 2;
    PH_FULL(bd, 0, { STG_A(bo, 1, k1); STG_B(bo, 1, k1); }, ((void)0));
    PH_A(bd, 1, { STG_A(bd, 0, k2); STG_B(bd, 0, k2); }, VMW4);
    PH_FULL(bo, 0, { STG_A(bd, 1, k2); STG_B(bd, 1, k2); }, ((void)0));
    PH_A(bo, 1, { STG_A(bo, 0, k3); STG_B(bo, 0, k3); }, VMW4);
  }
  {  // peeled last iteration
    const int k1 = ((NITER - 1) * 128 + 64) * 2;
    PH_FULL(bd, 0, { STG_A(bo, 1, k1); STG_B(bo, 1, k1); }, ((void)0));
    PH_A(bd, 1, ((void)0), VMW0);
    PH_FULL(bo, 0, ((void)0), ((void)0));
    PH_A(bo, 1, ((void)0), ((void)0));
  }

#pragma unroll
  for (int mi = 0; mi < 8; ++mi) {
    int row = m0 + (mi >> 2) * 128 + wr * 64 + (mi & 3) * 16 + hi4 * 4;
#pragma unroll
    for (int nj = 0; nj < 4; ++nj) {
      int col = n0 + (nj >> 1) * 128 + wc * 32 + (nj & 1) * 16 + lo16;
      float bv = bias ? bias[col] : 0.f;
#pragma unroll
      for (int j = 0; j < 4; ++j)
        C[(size_t)(row + j) * N + col] = acc[mi][nj][j] + bv;
    }
  }
}

// ---------------- slim LSTM step (round-5 form, best measured) ----------
// 512 blocks x 256 threads (2 blocks/CU). Block = one 16x16 output tile;
// 4 waves split K=1024; operands direct from global (L2-hot); xW loads
// hoisted; seq doubles as the h history.

__global__ __launch_bounds__(256) void lstm_step2_k(
    const float* __restrict__ xW,    // [2048][4096] (bias included)
    const u16* __restrict__ h_src,   // bf16, row b at h_src + b*h_stride
    int h_stride,
    const u16* __restrict__ UT2,     // [4096 permuted][1024] bf16
    float* __restrict__ c_ws,        // [32][1024] fp32 state (in/out)
    u16* __restrict__ seq,           // [2048][1024] bf16
    float* __restrict__ out_hc,      // final h,c (fp32) or nullptr
    int t) {
  __shared__ float Zs[4][16][17];
  const int tid = threadIdx.x;
  const int w = tid >> 6, lane = tid & 63;
  const int lo16 = lane & 15, hi4 = lane >> 4;
  const int zt = blockIdx.x >> 1;   // 0..255
  const int bt = blockIdx.x & 1;    // 0..1

  // hoisted xW prefetch (consumed after the z-reduce barrier)
  const int bb = tid >> 2, jg = tid & 3;
  float xw0 = 0.f, xw1 = 0.f, xw2 = 0.f, xw3 = 0.f;
  if (tid < 64) {
    const float* xrow =
        xW + (size_t)((bt * 16 + bb) * T_STEPS + t) * GDIM + zt * 4 + jg;
    xw0 = xrow[0];
    xw1 = xrow[1024];
    xw2 = xrow[2048];
    xw3 = xrow[3072];
  }

  const u16* arow = h_src + (size_t)(bt * 16 + lo16) * h_stride;
  const u16* brow = UT2 + (size_t)(zt * 16 + lo16) * HDIM;

  f32x4 acc = {};
#pragma unroll
  for (int kc = 0; kc < 8; ++kc) {
    int k = w * 256 + kc * 32 + hi4 * 8;
    bf16x8 a = *reinterpret_cast<const bf16x8*>(arow + k);
    bf16x8 b = *reinterpret_cast<const bf16x8*>(brow + k);
    acc = mfma16(a, b, acc);
  }
#pragma unroll
  for (int j = 0; j < 4; ++j) Zs[w][hi4 * 4 + j][lo16] = acc[j];
  __syncthreads();

  if (tid < 64) {
    int b = bt * 16 + bb;
    int hcol = zt * 4 + jg;
    float z[4] = {xw0, xw1, xw2, xw3};
#pragma unroll
    for (int g = 0; g < 4; ++g)
#pragma unroll
      for (int ww = 0; ww < 4; ++ww) z[g] += Zs[ww][bb][g * 4 + jg];
    size_t cidx = (size_t)b * HDIM + hcol;
    float c_old = c_ws[cidx];
    float ig = 1.f / (1.f + __expf(-z[0]));
    float fg = 1.f / (1.f + __expf(-z[1]));
    float gg = ftanh(z[2]);
    float og = 1.f / (1.f + __expf(-z[3]));
    float cn = fg * c_old + ig * gg;
    float hn = og * ftanh(cn);
    c_ws[cidx] = cn;
    seq[(size_t)(b * T_STEPS + t) * HDIM + hcol] = f2b(hn);
    if (out_hc) {
      out_hc[cidx] = hn;
      out_hc[BATCH * HDIM + cidx] = cn;
    }
  }
}

// ---------------- launcher ----------------

extern "C" void kernel_launch(void* const* d_in, const int* in_sizes, int n_in,
                              void* d_out, int out_size, void* d_ws,
                              size_t ws_size, hipStream_t stream) {
  const int* x = (const int*)d_in[0];
  const float* state_h = (const float*)d_in[1];
  const float* state_c = (const float*)d_in[2];
  const float* emb = (const float*)d_in[3];
  const float* W = (const float*)d_in[4];
  const float* U = (const float*)d_in[5];
  const float* bvec = (const float*)d_in[6];
  const float* dW = (const float*)d_in[7];
  const float* db = (const float*)d_in[8];
  float* out = (float*)d_out;
  char* ws = (char*)d_ws;

  size_t off = 0;
  auto alloc = [&](size_t bytes) {
    void* p = ws + off;
    off += (bytes + 255) & ~(size_t)255;
    return p;
  };
  u16* A_emb = (u16*)alloc(2048ull * EDIM * 2);      //  2.0 MB
  u16* WbT   = (u16*)alloc((size_t)GDIM * EDIM * 2); //  4.0 MB
  u16* UT2   = (u16*)alloc((size_t)GDIM * HDIM * 2); //  8.4 MB (permuted)
  u16* DbT   = (u16*)alloc((size_t)VDIM * HDIM * 2); // 65.5 MB
  float* xW  = (float*)alloc(2048ull * GDIM * 4);    // 33.6 MB
  u16* seq   = (u16*)alloc(2048ull * HDIM * 2);      //  4.2 MB
  u16* h0b   = (u16*)alloc((size_t)BATCH * HDIM * 2);
  float* c_ws = (float*)alloc((size_t)BATCH * HDIM * 4);
  if (off > ws_size) return;  // ~117.8 MB needed

  gather_init_k<<<1152, 256, 0, stream>>>(x, emb, A_emb, state_h, state_c,
                                          h0b, c_ws);
  transpose_cvt_k<<<dim3(GDIM / 64, EDIM / 64), 256, 0, stream>>>(W, WbT, EDIM, GDIM);
  transpose_cvt_permU_k<<<dim3(GDIM / 64, HDIM / 64), 256, 0, stream>>>(U, UT2);
  transpose_cvt_k<<<dim3(VDIM / 64, HDIM / 64), 256, 0, stream>>>(dW, DbT, HDIM, VDIM);

  // xW = emb @ W + b : [2048][4096] via the 256x256 pipeline (K=512)
  gemm256_k<<<dim3((2048 / 256) * (GDIM / 256)), 512, 0, stream>>>(
      A_emb, WbT, bvec, xW, 2048, GDIM, EDIM);

  // LSTM scan: 64 slim step kernels; seq is the h history
  for (int t = 0; t < T_STEPS; ++t) {
    const u16* h_src = (t == 0) ? h0b : (seq + (size_t)(t - 1) * HDIM);
    int h_stride = (t == 0) ? HDIM : T_STEPS * HDIM;
    float* outhc = (t == T_STEPS - 1) ? (out + 65536000ull) : nullptr;
    lstm_step2_k<<<512, 256, 0, stream>>>(xW, h_src, h_stride, UT2, c_ws, seq,
                                          outhc, t);
  }

  // logits = seq @ dense_W + dense_b : [2048][32000], 8x125=1000 blocks
  gemm256_k<<<dim3((2048 / 256) * (VDIM / 256)), 512, 0, stream>>>(
      seq, DbT, db, out, 2048, VDIM, HDIM);
}